// Round 6
// baseline (2220.289 us; speedup 1.0000x reference)
//
#include <hip/hip_runtime.h>
#include <hip/hip_bf16.h>
#include <math.h>

#define B 512
#define N 50
#define D 768
#define G4 3072
#define BN (B*N)        // 25600
#define FLAT (N*D)      // 38400
#define TCH 10          // timesteps per xg chunk
#define NCHUNK (N/TCH)  // 5
#define KC 1536         // fcross K (vsum|asum concat)
#define CCH 6400        // floats per egce chunk = 128 channels x 50

typedef __hip_bfloat16 bf16;
typedef short short8 __attribute__((ext_vector_type(8)));
typedef float floatx4 __attribute__((ext_vector_type(4)));

__device__ __forceinline__ float sigf(float x){ return 1.0f/(1.0f+expf(-x)); }
__device__ __forceinline__ float u2f(unsigned short u){ return __uint_as_float(((unsigned int)u)<<16); }
__device__ __forceinline__ unsigned short f2u(float f){ bf16 h=__float2bfloat16(f); return *(unsigned short*)&h; }

// ---- EGCE fused: coalesced chunked GAP + gates + gated v/a sums (one block/batch) --
__global__ __launch_bounds__(256) void egce_fused(
    const float* __restrict__ text, const int* __restrict__ vid, const int* __restrict__ aid,
    const float* __restrict__ vemb, const float* __restrict__ aemb, const float* __restrict__ egw,
    float* __restrict__ att_t, unsigned short* __restrict__ catAB){
  __shared__ float buf[CCH];
  __shared__ float gt[D+2], gv[D+2], ga[D+2];
  __shared__ float attvS[D], attaS[D];
  __shared__ int vidS[N], aidS[N];
  int b=blockIdx.x, tid=threadIdx.x;
  if(tid<N){ vidS[tid]=vid[b*N+tid]; aidS[tid]=aid[b*N+tid]; }
  if(tid==0){ gt[0]=gv[0]=ga[0]=0.f; gt[D+1]=gv[D+1]=ga[D+1]=0.f; }
  __syncthreads();
  const float* tb = text + (size_t)b*FLAT;
  for(int c=0;c<6;c++){
    int j0=c*CCH;
    // text: coalesced stage -> segmented sum from LDS
    for(int it=0;it<25;it++) buf[it*256+tid]=tb[j0+it*256+tid];
    __syncthreads();
    if(tid<128){ float s=0.f; for(int p=0;p<50;p++) s+=buf[tid*50+p]; gt[c*128+tid+1]=s*(1.f/50.f); }
    __syncthreads();
    // visual (gathered rows, coalesced within row)
    for(int it=0;it<25;it++){ int j=j0+it*256+tid; int n=j/D, d=j-n*D;
      float v=vemb[vidS[n]*D+d]; buf[it*256+tid]=v>0.f?v:0.f; }
    __syncthreads();
    if(tid<128){ float s=0.f; for(int p=0;p<50;p++) s+=buf[tid*50+p]; gv[c*128+tid+1]=s*(1.f/50.f); }
    __syncthreads();
    // acoustic
    for(int it=0;it<25;it++){ int j=j0+it*256+tid; int n=j/D, d=j-n*D;
      buf[it*256+tid]=aemb[aidS[n]*D+d]; }
    __syncthreads();
    if(tid<128){ float s=0.f; for(int p=0;p<50;p++) s+=buf[tid*50+p]; ga[c*128+tid+1]=s*(1.f/50.f); }
    __syncthreads();
  }
  float w0=egw[0],w1=egw[1],w2=egw[2];
  for(int ch=tid;ch<D;ch+=256){
    att_t[(size_t)b*D+ch]=sigf(w0*gt[ch]+w1*gt[ch+1]+w2*gt[ch+2]);
    attvS[ch]=sigf(w0*gv[ch]+w1*gv[ch+1]+w2*gv[ch+2]);
    attaS[ch]=sigf(w0*ga[ch]+w1*ga[ch+1]+w2*ga[ch+2]);
  }
  __syncthreads();
  // gated per-batch sums (rows are cache-hot from phase 1)
  float va[3]={0,0,0}, aa[3]={0,0,0};
  for(int n=0;n<N;n++){
    int idv=vidS[n], ida=aidS[n];
    #pragma unroll
    for(int q=0;q<3;q++){
      int d=q*256+tid;
      int ch=(n*D+d)/50;
      float vv=vemb[idv*D+d]; vv=vv>0.f?vv:0.f;
      va[q]+=vv*attvS[ch];
      aa[q]+=aemb[ida*D+d]*attaS[ch];
    }
  }
  for(int q=0;q<3;q++){
    int d=q*256+tid;
    catAB[(size_t)b*KC+d]    =f2u(va[q]);
    catAB[(size_t)b*KC+D+d]  =f2u(aa[q]);
  }
}

// ---- weight prep: LSTM gate-interleave n'=dg*4+g (bf16) + bias sums ----------------
__global__ __launch_bounds__(256) void prep_weights(
    const float* __restrict__ Wih, const float* __restrict__ Whh,
    const float* __restrict__ bih, const float* __restrict__ bhh,
    unsigned short* __restrict__ WihP, unsigned short* __restrict__ WhhP,
    float* __restrict__ bsum){
  int np = blockIdx.x;
  int dg = np>>2, g = np&3;
  size_t src = (size_t)(g*D+dg)*D;
  for(int k=threadIdx.x;k<D;k+=256){
    WihP[(size_t)np*D+k] = f2u(Wih[src+k]);
    WhhP[(size_t)np*D+k] = f2u(Whh[src+k]);
  }
  if(threadIdx.x==0) bsum[np] = bih[g*D+dg] + bhh[g*D+dg];
}

// ---- fcross weight prep ------------------------------------------------------------
__global__ __launch_bounds__(256) void prep_fcross(
    const float* __restrict__ vW, const float* __restrict__ vb,
    unsigned short* __restrict__ WcB, float* __restrict__ fb){
  int n = blockIdx.x;
  const float* W0 = vW; const float* W1 = vW + D*D; const float* W2 = vW + 2*D*D;
  for(int k=threadIdx.x;k<D;k+=256){
    WcB[(size_t)n*KC + k]     = f2u(W0[(size_t)n*D+k]);
    WcB[(size_t)n*KC + D + k] = f2u(W1[(size_t)n*D+k] + W2[(size_t)n*D+k]);
  }
  if(threadIdx.x==0) fb[n] = 50.f*(vb[n]+vb[D+n]+vb[2*D+n]);
}

// ---- fcross MFMA: fcross[b][n] = (catAB[b] . WcB[n] + fb[n]) / 3 -------------------
__global__ __launch_bounds__(256) void fcross_mfma(
    const unsigned short* __restrict__ catAB, const unsigned short* __restrict__ WcB,
    const float* __restrict__ fb, float* __restrict__ fcross){
  __shared__ unsigned short Ash[32*40];
  __shared__ unsigned short Bsh[64*40];
  int tid=threadIdx.x;
  int bx=blockIdx.x, by=blockIdx.y;
  int lane=tid&63, w=tid>>6;
  int l15=lane&15, lq=lane>>4;
  int arow=tid>>3, aseg=(tid&7)*4;
  int brow=tid>>2, bseg=(tid&3)*8;
  floatx4 acc0={},acc1={};
  const unsigned short* aG = catAB + (size_t)(by*32 + arow)*KC + aseg;
  const unsigned short* bG = WcB   + (size_t)(bx*64 + brow)*KC + bseg;
  for(int k0=0;k0<KC;k0+=32){
    *(uint2*)&Ash[arow*40 + aseg] = *(const uint2*)(aG + k0);
    *(uint4*)&Bsh[brow*40 + bseg] = *(const uint4*)(bG + k0);
    __syncthreads();
    short8 a0=*(const short8*)&Ash[l15*40 + lq*8];
    short8 a1=*(const short8*)&Ash[(16+l15)*40 + lq*8];
    short8 bb=*(const short8*)&Bsh[(w*16 + l15)*40 + lq*8];
    acc0=__builtin_amdgcn_mfma_f32_16x16x32_bf16(a0,bb,acc0,0,0,0);
    acc1=__builtin_amdgcn_mfma_f32_16x16x32_bf16(a1,bb,acc1,0,0,0);
    __syncthreads();
  }
  int n = bx*64 + w*16 + l15;
  float bias = fb[n];
  #pragma unroll
  for(int r=0;r<4;r++){
    int m0 = by*32 + lq*4 + r;
    fcross[(size_t)m0*D + n]      = (acc0[r] + bias)*(1.f/3.f);
    fcross[(size_t)(m0+16)*D + n] = (acc1[r] + bias)*(1.f/3.f);
  }
}

// ---- fused pre-LN + LayerNorm ------------------------------------------------------
__global__ __launch_bounds__(256) void fuse_ln(
    const float* __restrict__ text, const float* __restrict__ att_t,
    const float* __restrict__ fcross, const float* __restrict__ lng,
    const float* __restrict__ lnb, bf16* __restrict__ shift){
  int row = blockIdx.x;
  int b = row/N, n = row - b*N;
  int tid=threadIdx.x;
  float v[3];
  for(int q=0;q<3;q++){
    int d=q*256+tid;
    int ch=(n*D+d)/50;
    v[q] = text[(size_t)row*D+d]*att_t[(size_t)b*D+ch] + fcross[(size_t)b*D+d];
  }
  __shared__ float red[256];
  red[tid]=v[0]+v[1]+v[2]; __syncthreads();
  for(int st=128;st>0;st>>=1){ if(tid<st) red[tid]+=red[tid+st]; __syncthreads(); }
  float m = red[0]*(1.f/768.f);
  __syncthreads();
  float s2=0.f;
  for(int q=0;q<3;q++){ float dl=v[q]-m; s2+=dl*dl; }
  red[tid]=s2; __syncthreads();
  for(int st=128;st>0;st>>=1){ if(tid<st) red[tid]+=red[tid+st]; __syncthreads(); }
  float var = red[0]*(1.f/768.f);
  float rs = 1.f/sqrtf(var+1e-5f);
  for(int q=0;q<3;q++){
    int d=q*256+tid;
    shift[(size_t)row*D+d]=__float2bfloat16((v[q]-m)*rs*lng[d]+lnb[d]);
  }
}

// ---------------- zero init ---------------------------------------------------------
__global__ __launch_bounds__(256) void zero_init(float* __restrict__ cbuf, unsigned short* __restrict__ h0){
  size_t i=(size_t)blockIdx.x*256+threadIdx.x;
  if(i<(size_t)B*D){ cbuf[i]=0.f; h0[i]=0; }
}

// ---- xg chunk GEMM (MFMA, LDS-staged) ----------------------------------------------
__global__ __launch_bounds__(256) void xg_gemm_mfma(
    const unsigned short* __restrict__ shift, const unsigned short* __restrict__ WihP,
    const float* __restrict__ bsum, unsigned short* __restrict__ xgc, int c0){
  __shared__ unsigned short Ash[64*40];
  __shared__ unsigned short Bsh[64*40];
  int tid=threadIdx.x;
  int bx=blockIdx.x, by=blockIdx.y;
  int lane=tid&63, w=tid>>6;
  int wm=w&1, wn=w>>1;
  int srow=tid>>2, skg=(tid&3)*8;
  int l15=lane&15, lq=lane>>4;
  floatx4 acc[2][2]={};
  int R = by*64 + srow;
  int b = R/TCH; int tin = R - b*TCH;
  const unsigned short* aG = shift + ((size_t)b*N + c0 + tin)*D + skg;
  const unsigned short* bG = WihP + (size_t)(bx*64 + srow)*D + skg;
  for(int k0=0;k0<D;k0+=32){
    *(uint4*)&Ash[srow*40 + skg] = *(const uint4*)(aG + k0);
    *(uint4*)&Bsh[srow*40 + skg] = *(const uint4*)(bG + k0);
    __syncthreads();
    short8 a0=*(const short8*)&Ash[(wm*32 + l15)*40 + lq*8];
    short8 a1=*(const short8*)&Ash[(wm*32 + 16 + l15)*40 + lq*8];
    short8 b0=*(const short8*)&Bsh[(wn*32 + l15)*40 + lq*8];
    short8 b1=*(const short8*)&Bsh[(wn*32 + 16 + l15)*40 + lq*8];
    acc[0][0]=__builtin_amdgcn_mfma_f32_16x16x32_bf16(a0,b0,acc[0][0],0,0,0);
    acc[0][1]=__builtin_amdgcn_mfma_f32_16x16x32_bf16(a0,b1,acc[0][1],0,0,0);
    acc[1][0]=__builtin_amdgcn_mfma_f32_16x16x32_bf16(a1,b0,acc[1][0],0,0,0);
    acc[1][1]=__builtin_amdgcn_mfma_f32_16x16x32_bf16(a1,b1,acc[1][1],0,0,0);
    __syncthreads();
  }
  #pragma unroll
  for(int tm=0;tm<2;tm++){
    #pragma unroll
    for(int tn=0;tn<2;tn++){
      int n = bx*64 + wn*32 + tn*16 + l15;
      float bs = bsum[n];
      #pragma unroll
      for(int r=0;r<4;r++){
        int m = wm*32 + tm*16 + lq*4 + r;
        size_t Rg = (size_t)by*64 + m;
        xgc[Rg*G4 + n] = f2u(acc[tm][tn][r] + bs);
      }
    }
  }
}

// ---- LSTM step: barrier-free K-loop, direct global MFMA fragments, 64x64 tiles -----
__global__ __launch_bounds__(256) void lstm_step2(
    const unsigned short* __restrict__ hprev, unsigned short* __restrict__ hnext,
    float* __restrict__ cbuf, const unsigned short* __restrict__ xgc,
    const unsigned short* __restrict__ WhhP,
    const float* __restrict__ text, const float* __restrict__ att_t,
    float* __restrict__ out, int t, int tin){
  __shared__ float gbuf[64][68];
  int tid=threadIdx.x;
  int bx=blockIdx.x, by=blockIdx.y;   // bx: 48 n'-tiles of 64; by: 8 batch tiles of 64
  int lane=tid&63, w=tid>>6;
  int l15=lane&15, lq=lane>>4;
  floatx4 acc[4]={};
  const unsigned short* Bp = WhhP + (size_t)(bx*64 + w*16 + l15)*D + lq*8;
  const unsigned short* Ap = hprev + (size_t)(by*64 + l15)*D + lq*8;
  #pragma unroll 4
  for(int k0=0;k0<D;k0+=32){
    short8 bfr = *(const short8*)(Bp + k0);
    #pragma unroll
    for(int mi=0;mi<4;mi++){
      short8 afr = *(const short8*)(Ap + (size_t)mi*16*D + k0);
      acc[mi]=__builtin_amdgcn_mfma_f32_16x16x32_bf16(afr,bfr,acc[mi],0,0,0);
    }
  }
  #pragma unroll
  for(int mi=0;mi<4;mi++)
    #pragma unroll
    for(int r=0;r<4;r++)
      gbuf[mi*16 + lq*4 + r][w*16 + l15] = acc[mi][r];
  __syncthreads();
  for(int p=tid;p<1024;p+=256){
    int bl=p>>4, dgl=p&15;
    int b=by*64+bl, dg=bx*16+dgl;
    size_t xr=((size_t)b*TCH + tin)*G4 + bx*64 + dgl*4;
    float gi=gbuf[bl][dgl*4+0] + u2f(xgc[xr+0]);
    float gf=gbuf[bl][dgl*4+1] + u2f(xgc[xr+1]);
    float gg=gbuf[bl][dgl*4+2] + u2f(xgc[xr+2]);
    float go=gbuf[bl][dgl*4+3] + u2f(xgc[xr+3]);
    float c_old=cbuf[(size_t)b*D+dg];
    float cn=sigf(gf)*c_old + sigf(gi)*tanhf(gg);
    float hn=sigf(go)*tanhf(cn);
    cbuf[(size_t)b*D+dg]=cn;
    hnext[(size_t)b*D+dg]=f2u(hn);
    size_t oidx=((size_t)b*N+t)*D+dg;
    int ch=(t*D+dg)/50;
    out[oidx]=hn + text[oidx]*att_t[(size_t)b*D+ch];
  }
}

extern "C" void kernel_launch(void* const* d_in, const int* in_sizes, int n_in,
                              void* d_out, int out_size, void* d_ws, size_t ws_size,
                              hipStream_t stream){
  const float* text=(const float*)d_in[0];
  const int*  vid =(const int*) d_in[1];
  const int*  aid =(const int*) d_in[2];
  const float* vemb=(const float*)d_in[3];
  const float* aemb=(const float*)d_in[4];
  const float* egw =(const float*)d_in[5];
  const float* Wih =(const float*)d_in[6];
  const float* Whh =(const float*)d_in[7];
  const float* bih =(const float*)d_in[8];
  const float* bhh =(const float*)d_in[9];
  const float* lng =(const float*)d_in[10];
  const float* lnb =(const float*)d_in[11];
  const float* vW  =(const float*)d_in[20];
  const float* vb  =(const float*)d_in[21];
  float* out = (float*)d_out;

  // ---- workspace layout (~91 MB, inside proven-safe region) ----
  float* W = (float*)d_ws;
  const size_t S = (size_t)B*D;
  float* att_t = W;
  float* fcross= att_t + S;
  float* cbuf  = fcross + S;
  float* bsum  = cbuf + S;               // G4
  float* fb    = bsum + G4;              // D
  unsigned short* WihP = (unsigned short*)(fb + D);      // G4*D
  unsigned short* WhhP = WihP + (size_t)G4*D;            // G4*D
  unsigned short* WcB  = WhhP + (size_t)G4*D;            // D*KC
  unsigned short* catAB= WcB + (size_t)D*KC;             // B*KC
  unsigned short* hA0  = catAB + (size_t)B*KC;           // S
  unsigned short* hA1  = hA0 + S;                        // S
  bf16*  shift = (bf16*)(hA1 + S);                       // BN*D
  unsigned short* xgc  = (unsigned short*)(shift + (size_t)BN*D); // B*TCH*G4

  prep_weights<<<G4,256,0,stream>>>(Wih,Whh,bih,bhh,WihP,WhhP,bsum);
  prep_fcross<<<D,256,0,stream>>>(vW,vb,WcB,fb);
  egce_fused<<<B,256,0,stream>>>(text,vid,aid,vemb,aemb,egw,att_t,catAB);
  fcross_mfma<<<dim3(12,16),256,0,stream>>>(catAB,WcB,fb,fcross);
  fuse_ln<<<BN,256,0,stream>>>(text,att_t,fcross,lng,lnb,shift);
  zero_init<<<(unsigned)((S+255)/256),256,0,stream>>>(cbuf,hA0);

  int t=0;
  for(int c=0;c<NCHUNK;c++){
    xg_gemm_mfma<<<dim3(48, (B*TCH)/64),256,0,stream>>>((const unsigned short*)shift,WihP,bsum,xgc,c*TCH);
    for(int ti=0;ti<TCH;ti++,t++){
      unsigned short* hp = (t&1)? hA1 : hA0;
      unsigned short* hn = (t&1)? hA0 : hA1;
      lstm_step2<<<dim3(48,8),256,0,stream>>>(hp,hn,cbuf,xgc,WhhP,text,att_t,out,t,ti);
    }
  }
}

// Round 7
// 1256.015 us; speedup vs baseline: 1.7677x; 1.7677x over previous
//
#include <hip/hip_runtime.h>
#include <hip/hip_bf16.h>
#include <math.h>

#define B 512
#define N 50
#define D 768
#define G4 3072
#define BN (B*N)        // 25600
#define FLAT (N*D)      // 38400
#define TCH 10          // timesteps per xg chunk
#define NCHUNK (N/TCH)  // 5
#define KC 1536         // fcross K (vsum|asum concat)
#define CCH 6400        // floats per egce chunk = 128 channels x 50

typedef __hip_bfloat16 bf16;
typedef short short8 __attribute__((ext_vector_type(8)));
typedef float floatx4 __attribute__((ext_vector_type(4)));

__device__ __forceinline__ float sigf(float x){ return 1.0f/(1.0f+expf(-x)); }
__device__ __forceinline__ float u2f(unsigned short u){ return __uint_as_float(((unsigned int)u)<<16); }
__device__ __forceinline__ unsigned short f2u(float f){ bf16 h=__float2bfloat16(f); return *(unsigned short*)&h; }

#define GLD16(g,l) __builtin_amdgcn_global_load_lds( \
    (const __attribute__((address_space(1))) unsigned int*)(g), \
    (__attribute__((address_space(3))) unsigned int*)(l), 16, 0, 0)

// ---- EGCE fused: coalesced chunked GAP + gates + gated v/a sums (one block/batch) --
__global__ __launch_bounds__(256) void egce_fused(
    const float* __restrict__ text, const int* __restrict__ vid, const int* __restrict__ aid,
    const float* __restrict__ vemb, const float* __restrict__ aemb, const float* __restrict__ egw,
    float* __restrict__ att_t, unsigned short* __restrict__ catAB){
  __shared__ float buf[CCH];
  __shared__ float gt[D+2], gv[D+2], ga[D+2];
  __shared__ float attvS[D], attaS[D];
  __shared__ int vidS[N], aidS[N];
  int b=blockIdx.x, tid=threadIdx.x;
  if(tid<N){ vidS[tid]=vid[b*N+tid]; aidS[tid]=aid[b*N+tid]; }
  if(tid==0){ gt[0]=gv[0]=ga[0]=0.f; gt[D+1]=gv[D+1]=ga[D+1]=0.f; }
  __syncthreads();
  const float* tb = text + (size_t)b*FLAT;
  for(int c=0;c<6;c++){
    int j0=c*CCH;
    for(int it=0;it<25;it++) buf[it*256+tid]=tb[j0+it*256+tid];
    __syncthreads();
    if(tid<128){ float s=0.f; for(int p=0;p<50;p++) s+=buf[tid*50+p]; gt[c*128+tid+1]=s*(1.f/50.f); }
    __syncthreads();
    for(int it=0;it<25;it++){ int j=j0+it*256+tid; int n=j/D, d=j-n*D;
      float v=vemb[vidS[n]*D+d]; buf[it*256+tid]=v>0.f?v:0.f; }
    __syncthreads();
    if(tid<128){ float s=0.f; for(int p=0;p<50;p++) s+=buf[tid*50+p]; gv[c*128+tid+1]=s*(1.f/50.f); }
    __syncthreads();
    for(int it=0;it<25;it++){ int j=j0+it*256+tid; int n=j/D, d=j-n*D;
      buf[it*256+tid]=aemb[aidS[n]*D+d]; }
    __syncthreads();
    if(tid<128){ float s=0.f; for(int p=0;p<50;p++) s+=buf[tid*50+p]; ga[c*128+tid+1]=s*(1.f/50.f); }
    __syncthreads();
  }
  float w0=egw[0],w1=egw[1],w2=egw[2];
  for(int ch=tid;ch<D;ch+=256){
    att_t[(size_t)b*D+ch]=sigf(w0*gt[ch]+w1*gt[ch+1]+w2*gt[ch+2]);
    attvS[ch]=sigf(w0*gv[ch]+w1*gv[ch+1]+w2*gv[ch+2]);
    attaS[ch]=sigf(w0*ga[ch]+w1*ga[ch+1]+w2*ga[ch+2]);
  }
  __syncthreads();
  float va[3]={0,0,0}, aa[3]={0,0,0};
  for(int n=0;n<N;n++){
    int idv=vidS[n], ida=aidS[n];
    #pragma unroll
    for(int q=0;q<3;q++){
      int d=q*256+tid;
      int ch=(n*D+d)/50;
      float vv=vemb[idv*D+d]; vv=vv>0.f?vv:0.f;
      va[q]+=vv*attvS[ch];
      aa[q]+=aemb[ida*D+d]*attaS[ch];
    }
  }
  for(int q=0;q<3;q++){
    int d=q*256+tid;
    catAB[(size_t)b*KC+d]    =f2u(va[q]);
    catAB[(size_t)b*KC+D+d]  =f2u(aa[q]);
  }
}

// ---- weight prep: LSTM gate-interleave n'=dg*4+g (bf16) + bias sums ----------------
__global__ __launch_bounds__(256) void prep_weights(
    const float* __restrict__ Wih, const float* __restrict__ Whh,
    const float* __restrict__ bih, const float* __restrict__ bhh,
    unsigned short* __restrict__ WihP, unsigned short* __restrict__ WhhP,
    float* __restrict__ bsum){
  int np = blockIdx.x;
  int dg = np>>2, g = np&3;
  size_t src = (size_t)(g*D+dg)*D;
  for(int k=threadIdx.x;k<D;k+=256){
    WihP[(size_t)np*D+k] = f2u(Wih[src+k]);
    WhhP[(size_t)np*D+k] = f2u(Whh[src+k]);
  }
  if(threadIdx.x==0) bsum[np] = bih[g*D+dg] + bhh[g*D+dg];
}

// ---- fcross weight prep ------------------------------------------------------------
__global__ __launch_bounds__(256) void prep_fcross(
    const float* __restrict__ vW, const float* __restrict__ vb,
    unsigned short* __restrict__ WcB, float* __restrict__ fb){
  int n = blockIdx.x;
  const float* W0 = vW; const float* W1 = vW + D*D; const float* W2 = vW + 2*D*D;
  for(int k=threadIdx.x;k<D;k+=256){
    WcB[(size_t)n*KC + k]     = f2u(W0[(size_t)n*D+k]);
    WcB[(size_t)n*KC + D + k] = f2u(W1[(size_t)n*D+k] + W2[(size_t)n*D+k]);
  }
  if(threadIdx.x==0) fb[n] = 50.f*(vb[n]+vb[D+n]+vb[2*D+n]);
}

// ---- fcross MFMA -------------------------------------------------------------------
__global__ __launch_bounds__(256) void fcross_mfma(
    const unsigned short* __restrict__ catAB, const unsigned short* __restrict__ WcB,
    const float* __restrict__ fb, float* __restrict__ fcross){
  __shared__ unsigned short Ash[32*40];
  __shared__ unsigned short Bsh[64*40];
  int tid=threadIdx.x;
  int bx=blockIdx.x, by=blockIdx.y;
  int lane=tid&63, w=tid>>6;
  int l15=lane&15, lq=lane>>4;
  int arow=tid>>3, aseg=(tid&7)*4;
  int brow=tid>>2, bseg=(tid&3)*8;
  floatx4 acc0={},acc1={};
  const unsigned short* aG = catAB + (size_t)(by*32 + arow)*KC + aseg;
  const unsigned short* bG = WcB   + (size_t)(bx*64 + brow)*KC + bseg;
  for(int k0=0;k0<KC;k0+=32){
    *(uint2*)&Ash[arow*40 + aseg] = *(const uint2*)(aG + k0);
    *(uint4*)&Bsh[brow*40 + bseg] = *(const uint4*)(bG + k0);
    __syncthreads();
    short8 a0=*(const short8*)&Ash[l15*40 + lq*8];
    short8 a1=*(const short8*)&Ash[(16+l15)*40 + lq*8];
    short8 bb=*(const short8*)&Bsh[(w*16 + l15)*40 + lq*8];
    acc0=__builtin_amdgcn_mfma_f32_16x16x32_bf16(a0,bb,acc0,0,0,0);
    acc1=__builtin_amdgcn_mfma_f32_16x16x32_bf16(a1,bb,acc1,0,0,0);
    __syncthreads();
  }
  int n = bx*64 + w*16 + l15;
  float bias = fb[n];
  #pragma unroll
  for(int r=0;r<4;r++){
    int m0 = by*32 + lq*4 + r;
    fcross[(size_t)m0*D + n]      = (acc0[r] + bias)*(1.f/3.f);
    fcross[(size_t)(m0+16)*D + n] = (acc1[r] + bias)*(1.f/3.f);
  }
}

// ---- fused pre-LN + LayerNorm ------------------------------------------------------
__global__ __launch_bounds__(256) void fuse_ln(
    const float* __restrict__ text, const float* __restrict__ att_t,
    const float* __restrict__ fcross, const float* __restrict__ lng,
    const float* __restrict__ lnb, bf16* __restrict__ shift){
  int row = blockIdx.x;
  int b = row/N, n = row - b*N;
  int tid=threadIdx.x;
  float v[3];
  for(int q=0;q<3;q++){
    int d=q*256+tid;
    int ch=(n*D+d)/50;
    v[q] = text[(size_t)row*D+d]*att_t[(size_t)b*D+ch] + fcross[(size_t)b*D+d];
  }
  __shared__ float red[256];
  red[tid]=v[0]+v[1]+v[2]; __syncthreads();
  for(int st=128;st>0;st>>=1){ if(tid<st) red[tid]+=red[tid+st]; __syncthreads(); }
  float m = red[0]*(1.f/768.f);
  __syncthreads();
  float s2=0.f;
  for(int q=0;q<3;q++){ float dl=v[q]-m; s2+=dl*dl; }
  red[tid]=s2; __syncthreads();
  for(int st=128;st>0;st>>=1){ if(tid<st) red[tid]+=red[tid+st]; __syncthreads(); }
  float var = red[0]*(1.f/768.f);
  float rs = 1.f/sqrtf(var+1e-5f);
  for(int q=0;q<3;q++){
    int d=q*256+tid;
    shift[(size_t)row*D+d]=__float2bfloat16((v[q]-m)*rs*lng[d]+lnb[d]);
  }
}

// ---------------- zero init ---------------------------------------------------------
__global__ __launch_bounds__(256) void zero_init(float* __restrict__ cbuf, unsigned short* __restrict__ h0){
  size_t i=(size_t)blockIdx.x*256+threadIdx.x;
  if(i<(size_t)B*D){ cbuf[i]=0.f; h0[i]=0; }
}

// ---- xg chunk GEMM, m97 structure: 128x128 tile, BK=32, global_load_lds width=16 ---
// M=B*TCH=5120 (by 0..39), N=G4=3072 (bx 0..23), K=768.
__global__ __launch_bounds__(256) void xg_gemm_m97(
    const unsigned short* __restrict__ shift, const unsigned short* __restrict__ WihP,
    const float* __restrict__ bsum, unsigned short* __restrict__ xgc, int c0){
  __shared__ unsigned short Ash[128*32];   // 8 KB, contiguous (global_load_lds layout)
  __shared__ unsigned short Bsh[128*32];   // 8 KB
  int tid=threadIdx.x;
  int bx=blockIdx.x, by=blockIdx.y;
  int lane=tid&63, w=tid>>6;
  int wm=w&1, wn=w>>1;
  int l15=lane&15, lq=lane>>4;
  int srow=tid>>2, scol=(tid&3)*8;         // stage: row, col-segment (8 shorts = 16 B)
  // A global rows (token mapping R -> (b, tin))
  int R0 = by*128 + srow;
  int b0 = R0/TCH, t0 = R0 - b0*TCH;
  int R1 = R0 + 64;
  int b1 = R1/TCH, t1 = R1 - b1*TCH;
  const unsigned short* aG0 = shift + ((size_t)b0*N + c0 + t0)*D + scol;
  const unsigned short* aG1 = shift + ((size_t)b1*N + c0 + t1)*D + scol;
  const unsigned short* bG0 = WihP + (size_t)(bx*128 + srow)*D + scol;
  const unsigned short* bG1 = WihP + (size_t)(bx*128 + srow + 64)*D + scol;
  unsigned short* aL0 = &Ash[srow*32 + scol];
  unsigned short* aL1 = &Ash[(srow+64)*32 + scol];
  unsigned short* bL0 = &Bsh[srow*32 + scol];
  unsigned short* bL1 = &Bsh[(srow+64)*32 + scol];
  floatx4 acc[4][4]={};
  for(int k0=0;k0<D;k0+=32){
    GLD16(aG0+k0, aL0);
    GLD16(aG1+k0, aL1);
    GLD16(bG0+k0, bL0);
    GLD16(bG1+k0, bL1);
    __syncthreads();
    short8 af[4], bf[4];
    #pragma unroll
    for(int i=0;i<4;i++){
      af[i]=*(const short8*)&Ash[(wm*64 + i*16 + l15)*32 + lq*8];
      bf[i]=*(const short8*)&Bsh[(wn*64 + i*16 + l15)*32 + lq*8];
    }
    #pragma unroll
    for(int mi=0;mi<4;mi++)
      #pragma unroll
      for(int ni=0;ni<4;ni++)
        acc[mi][ni]=__builtin_amdgcn_mfma_f32_16x16x32_bf16(af[mi],bf[ni],acc[mi][ni],0,0,0);
    __syncthreads();
  }
  #pragma unroll
  for(int ni=0;ni<4;ni++){
    int n = bx*128 + wn*64 + ni*16 + l15;
    float bs = bsum[n];
    #pragma unroll
    for(int mi=0;mi<4;mi++){
      #pragma unroll
      for(int r=0;r<4;r++){
        size_t m = (size_t)by*128 + wm*64 + mi*16 + lq*4 + r;
        xgc[m*G4 + n] = f2u(acc[mi][ni][r] + bs);
      }
    }
  }
}

// ---- LSTM step (R5 proven version: LDS-staged MFMA, 32x64 tiles, grid (48,16)) -----
__global__ __launch_bounds__(256) void lstm_step_mfma(
    const unsigned short* __restrict__ hprev, unsigned short* __restrict__ hnext,
    float* __restrict__ cbuf, const unsigned short* __restrict__ xgc,
    const unsigned short* __restrict__ WhhP,
    const float* __restrict__ text, const float* __restrict__ att_t,
    float* __restrict__ out, int t, int tin){
  __shared__ unsigned short Ash[32*40];
  __shared__ unsigned short Bsh[64*40];
  __shared__ float gbuf[32][65];
  int tid=threadIdx.x;
  int bx=blockIdx.x, by=blockIdx.y;
  int lane=tid&63, w=tid>>6;
  int l15=lane&15, lq=lane>>4;
  int arow=tid>>3, aseg=(tid&7)*4;
  int brow=tid>>2, bseg=(tid&3)*8;
  floatx4 acc0={},acc1={};
  const unsigned short* aG = hprev + (size_t)(by*32 + arow)*D + aseg;
  const unsigned short* bG = WhhP + (size_t)(bx*64 + brow)*D + bseg;
  for(int k0=0;k0<D;k0+=32){
    *(uint2*)&Ash[arow*40 + aseg] = *(const uint2*)(aG + k0);
    *(uint4*)&Bsh[brow*40 + bseg] = *(const uint4*)(bG + k0);
    __syncthreads();
    short8 a0=*(const short8*)&Ash[l15*40 + lq*8];
    short8 a1=*(const short8*)&Ash[(16+l15)*40 + lq*8];
    short8 bb=*(const short8*)&Bsh[(w*16 + l15)*40 + lq*8];
    acc0=__builtin_amdgcn_mfma_f32_16x16x32_bf16(a0,bb,acc0,0,0,0);
    acc1=__builtin_amdgcn_mfma_f32_16x16x32_bf16(a1,bb,acc1,0,0,0);
    __syncthreads();
  }
  {
    int n = w*16 + l15;
    #pragma unroll
    for(int r=0;r<4;r++){
      gbuf[lq*4+r][n]      = acc0[r];
      gbuf[16+lq*4+r][n]   = acc1[r];
    }
  }
  __syncthreads();
  for(int p=tid;p<512;p+=256){
    int bl=p>>4, dgl=p&15;
    int b=by*32+bl, dg=bx*16+dgl;
    size_t xr=((size_t)b*TCH + tin)*G4 + bx*64 + dgl*4;
    float gi=gbuf[bl][dgl*4+0] + u2f(xgc[xr+0]);
    float gf=gbuf[bl][dgl*4+1] + u2f(xgc[xr+1]);
    float gg=gbuf[bl][dgl*4+2] + u2f(xgc[xr+2]);
    float go=gbuf[bl][dgl*4+3] + u2f(xgc[xr+3]);
    float c_old=cbuf[(size_t)b*D+dg];
    float cn=sigf(gf)*c_old + sigf(gi)*tanhf(gg);
    float hn=sigf(go)*tanhf(cn);
    cbuf[(size_t)b*D+dg]=cn;
    hnext[(size_t)b*D+dg]=f2u(hn);
    size_t oidx=((size_t)b*N+t)*D+dg;
    int ch=(t*D+dg)/50;
    out[oidx]=hn + text[oidx]*att_t[(size_t)b*D+ch];
  }
}

extern "C" void kernel_launch(void* const* d_in, const int* in_sizes, int n_in,
                              void* d_out, int out_size, void* d_ws, size_t ws_size,
                              hipStream_t stream){
  const float* text=(const float*)d_in[0];
  const int*  vid =(const int*) d_in[1];
  const int*  aid =(const int*) d_in[2];
  const float* vemb=(const float*)d_in[3];
  const float* aemb=(const float*)d_in[4];
  const float* egw =(const float*)d_in[5];
  const float* Wih =(const float*)d_in[6];
  const float* Whh =(const float*)d_in[7];
  const float* bih =(const float*)d_in[8];
  const float* bhh =(const float*)d_in[9];
  const float* lng =(const float*)d_in[10];
  const float* lnb =(const float*)d_in[11];
  const float* vW  =(const float*)d_in[20];
  const float* vb  =(const float*)d_in[21];
  float* out = (float*)d_out;

  // ---- workspace layout (~91 MB, proven safe) ----
  float* W = (float*)d_ws;
  const size_t S = (size_t)B*D;
  float* att_t = W;
  float* fcross= att_t + S;
  float* cbuf  = fcross + S;
  float* bsum  = cbuf + S;               // G4
  float* fb    = bsum + G4;              // D
  unsigned short* WihP = (unsigned short*)(fb + D);      // G4*D
  unsigned short* WhhP = WihP + (size_t)G4*D;            // G4*D
  unsigned short* WcB  = WhhP + (size_t)G4*D;            // D*KC
  unsigned short* catAB= WcB + (size_t)D*KC;             // B*KC
  unsigned short* hA0  = catAB + (size_t)B*KC;           // S
  unsigned short* hA1  = hA0 + S;                        // S
  bf16*  shift = (bf16*)(hA1 + S);                       // BN*D
  unsigned short* xgc  = (unsigned short*)(shift + (size_t)BN*D); // B*TCH*G4

  prep_weights<<<G4,256,0,stream>>>(Wih,Whh,bih,bhh,WihP,WhhP,bsum);
  prep_fcross<<<D,256,0,stream>>>(vW,vb,WcB,fb);
  egce_fused<<<B,256,0,stream>>>(text,vid,aid,vemb,aemb,egw,att_t,catAB);
  fcross_mfma<<<dim3(12,16),256,0,stream>>>(catAB,WcB,fb,fcross);
  fuse_ln<<<BN,256,0,stream>>>(text,att_t,fcross,lng,lnb,shift);
  zero_init<<<(unsigned)((S+255)/256),256,0,stream>>>(cbuf,hA0);

  int t=0;
  for(int c=0;c<NCHUNK;c++){
    xg_gemm_m97<<<dim3(24, 40),256,0,stream>>>((const unsigned short*)shift,WihP,bsum,xgc,c*TCH);
    for(int ti=0;ti<TCH;ti++,t++){
      unsigned short* hp = (t&1)? hA1 : hA0;
      unsigned short* hn = (t&1)? hA0 : hA1;
      lstm_step_mfma<<<dim3(48,16),256,0,stream>>>(hp,hn,cbuf,xgc,WhhP,text,att_t,out,t,ti);
    }
  }
}